// Round 1
// baseline (178.348 us; speedup 1.0000x reference)
//
#include <hip/hip_runtime.h>
#include <hip/hip_bf16.h>

#define BB 64
#define TT 512
#define HH 256
#define EE 128
#define VV 32000
#define SS 128
#define LL 16

// ---------- A1: hW[b,h] = attn_b[h] + sum_k last_hidden[b,k]*attn_W[h,k] ----------
__global__ __launch_bounds__(HH) void k_hw(const float* __restrict__ last_hidden,
                                           const float* __restrict__ attn_W,
                                           const float* __restrict__ attn_b,
                                           float* __restrict__ hW) {
    int b = blockIdx.x;
    int h = threadIdx.x;
    __shared__ float lh[HH];
    lh[h] = last_hidden[b * HH + h];
    __syncthreads();
    const float4* wrow = (const float4*)(attn_W + (size_t)h * (2 * HH));
    float acc = attn_b[h];
    for (int k4 = 0; k4 < HH / 4; ++k4) {
        float4 w = wrow[k4];
        acc += lh[k4*4+0]*w.x + lh[k4*4+1]*w.y + lh[k4*4+2]*w.z + lh[k4*4+3]*w.w;
    }
    hW[b * HH + h] = acc;
}

// ---------- A2: embed_z[b,:] = e + e @ ctrl_W.T + ctrl_b, e = emb_W[z_tm1[b]] ----------
__global__ __launch_bounds__(EE) void k_embed(const int* __restrict__ z_tm1,
                                              const float* __restrict__ emb_W,
                                              const float* __restrict__ ctrl_W,
                                              const float* __restrict__ ctrl_b,
                                              float* __restrict__ embed) {
    int b = blockIdx.x;
    int j = threadIdx.x;  // 128
    __shared__ float e[EE];
    int z = z_tm1[b];
    e[j] = emb_W[(size_t)z * EE + j];
    __syncthreads();
    const float4* wrow = (const float4*)(ctrl_W + (size_t)j * EE);
    float acc = ctrl_b[j] + e[j];
    for (int k4 = 0; k4 < EE / 4; ++k4) {
        float4 w = wrow[k4];
        acc += e[k4*4+0]*w.x + e[k4*4+1]*w.y + e[k4*4+2]*w.z + e[k4*4+3]*w.w;
    }
    embed[b * EE + j] = acc;
}

// ---------- B: scores[i] = sum_h v[h]*tanh(hW[b,h] + sum_k enc[i,k]*attn_W[h,HH+k]) ----------
// rows i = t*B + b (contiguous rows of u_enc_out); 64 rows per block, 4 waves,
// each wave owns 16 rows, each lane owns 4 output columns h.
__global__ __launch_bounds__(256) void k_scores(const float* __restrict__ enc,
                                                const float* __restrict__ attn_W,
                                                const float* __restrict__ attn_v,
                                                const float* __restrict__ hW,
                                                float* __restrict__ scores) {
    __shared__ float lds[64 * HH];  // 64 KB
    int i0 = blockIdx.x * 64;
    int tid = threadIdx.x;
    const float4* src = (const float4*)(enc + (size_t)i0 * HH);
    float4* dst = (float4*)lds;
    for (int idx = tid; idx < 64 * HH / 4; idx += 256) dst[idx] = src[idx];
    __syncthreads();

    int wid = tid >> 6, lane = tid & 63;
    int h0 = lane * 4;
    float4 v4 = *(const float4*)(attn_v + h0);

    float acc[16][4];
#pragma unroll
    for (int r = 0; r < 16; ++r)
#pragma unroll
        for (int hh = 0; hh < 4; ++hh) acc[r][hh] = 0.f;

    for (int kb = 0; kb < HH / 4; ++kb) {
        float4 w0 = *(const float4*)(attn_W + (size_t)(h0+0)*2*HH + HH + kb*4);
        float4 w1 = *(const float4*)(attn_W + (size_t)(h0+1)*2*HH + HH + kb*4);
        float4 w2 = *(const float4*)(attn_W + (size_t)(h0+2)*2*HH + HH + kb*4);
        float4 w3 = *(const float4*)(attn_W + (size_t)(h0+3)*2*HH + HH + kb*4);
#pragma unroll
        for (int r = 0; r < 16; ++r) {
            float4 e4 = *(const float4*)&lds[(wid*16 + r) * HH + kb*4];
            acc[r][0] += e4.x*w0.x + e4.y*w0.y + e4.z*w0.z + e4.w*w0.w;
            acc[r][1] += e4.x*w1.x + e4.y*w1.y + e4.z*w1.z + e4.w*w1.w;
            acc[r][2] += e4.x*w2.x + e4.y*w2.y + e4.z*w2.z + e4.w*w2.w;
            acc[r][3] += e4.x*w3.x + e4.y*w3.y + e4.z*w3.z + e4.w*w3.w;
        }
    }

#pragma unroll
    for (int r = 0; r < 16; ++r) {
        int i = i0 + wid * 16 + r;
        int b = i & (BB - 1);
        const float* hwb = hW + (size_t)b * HH + h0;
        float val = v4.x * tanhf(acc[r][0] + hwb[0])
                  + v4.y * tanhf(acc[r][1] + hwb[1])
                  + v4.z * tanhf(acc[r][2] + hwb[2])
                  + v4.w * tanhf(acc[r][3] + hwb[3]);
        for (int off = 32; off; off >>= 1) val += __shfl_xor(val, off, 64);
        if (lane == 0) scores[i] = val;
    }
}

// ---------- C1: softmax over T per b ----------
__global__ __launch_bounds__(256) void k_softmax(const float* __restrict__ scores,
                                                 float* __restrict__ wgt) {
    int b = blockIdx.x, tid = threadIdx.x;
    __shared__ float red[256];
    float s0 = scores[tid * BB + b];
    float s1 = scores[(tid + 256) * BB + b];
    red[tid] = fmaxf(s0, s1);
    __syncthreads();
    for (int off = 128; off; off >>= 1) {
        if (tid < off) red[tid] = fmaxf(red[tid], red[tid + off]);
        __syncthreads();
    }
    float m = red[0];
    __syncthreads();
    float e0 = expf(s0 - m), e1 = expf(s1 - m);
    red[tid] = e0 + e1;
    __syncthreads();
    for (int off = 128; off; off >>= 1) {
        if (tid < off) red[tid] += red[tid + off];
        __syncthreads();
    }
    float inv = 1.f / red[0];
    wgt[tid * BB + b] = e0 * inv;
    wgt[(tid + 256) * BB + b] = e1 * inv;
}

// ---------- C2: context partials over t-chunks ----------
__global__ __launch_bounds__(HH) void k_ctx_partial(const float* __restrict__ enc,
                                                    const float* __restrict__ wgt,
                                                    float* __restrict__ partial) {
    int c = blockIdx.x;   // 0..7
    int b = blockIdx.y;   // 0..63
    int h = threadIdx.x;  // 0..255
    float acc = 0.f;
    for (int t = c * 64; t < c * 64 + 64; ++t) {
        acc += wgt[t * BB + b] * enc[((size_t)t * BB + b) * HH + h];
    }
    partial[((size_t)c * BB + b) * HH + h] = acc;
}

// ---------- D: hidden = relu(ffnn_in @ Whid.T + bhid) ----------
__global__ __launch_bounds__(HH) void k_hidden(const float* __restrict__ embed,
                                               const float* __restrict__ partial,
                                               const float* __restrict__ last_hidden,
                                               const float* __restrict__ Whid,
                                               const float* __restrict__ bhid,
                                               float* __restrict__ hidden_ws,
                                               float* __restrict__ out_hidden) {
    int b = blockIdx.x;
    int tid = threadIdx.x;  // 256
    __shared__ float fin[2 * HH + EE];  // 640
    for (int j = tid; j < 2 * HH + EE; j += 256) {
        float vv;
        if (j < EE) {
            vv = embed[b * EE + j];
        } else if (j < EE + HH) {
            float s = 0.f;
            for (int c = 0; c < 8; ++c) s += partial[((size_t)c * BB + b) * HH + (j - EE)];
            vv = s;
        } else {
            vv = last_hidden[b * HH + (j - EE - HH)];
        }
        fin[j] = vv;
    }
    __syncthreads();
    const float4* wrow = (const float4*)(Whid + (size_t)tid * (2 * HH + EE));
    float acc = bhid[tid];
    for (int k4 = 0; k4 < (2 * HH + EE) / 4; ++k4) {
        float4 w = wrow[k4];
        acc += fin[k4*4+0]*w.x + fin[k4*4+1]*w.y + fin[k4*4+2]*w.z + fin[k4*4+3]*w.w;
    }
    acc = fmaxf(acc, 0.f);
    hidden_ws[b * HH + tid] = acc;
    out_hidden[b * HH + tid] = acc;
}

// ---------- E: gen_score = relu(hidden @ Wout.T + bout) ----------
__global__ __launch_bounds__(SS) void k_gen(const float* __restrict__ hidden,
                                            const float* __restrict__ Wout,
                                            const float* __restrict__ bout,
                                            float* __restrict__ gen) {
    int b = blockIdx.x;
    int s = threadIdx.x;  // 128
    __shared__ float hsh[HH];
    hsh[s] = hidden[b * HH + s];
    hsh[s + 128] = hidden[b * HH + s + 128];
    __syncthreads();
    const float4* wrow = (const float4*)(Wout + (size_t)s * HH);
    float acc = bout[s];
    for (int k4 = 0; k4 < HH / 4; ++k4) {
        float4 w = wrow[k4];
        acc += hsh[k4*4+0]*w.x + hsh[k4*4+1]*w.y + hsh[k4*4+2]*w.z + hsh[k4*4+3]*w.w;
    }
    gen[b * SS + s] = fmaxf(acc, 0.f);
}

// ---------- F: probas rows — analytic softmax of (-0.01 + scatter) ----------
__global__ __launch_bounds__(256) void k_probas(const int* __restrict__ slot,
                                                const float* __restrict__ gen,
                                                float* __restrict__ out) {
    int l = blockIdx.x / BB;
    int b = blockIdx.x % BB;
    int tid = threadIdx.x;
    __shared__ int cols[SS];
    __shared__ float gv[SS];
    __shared__ float red[256];
    if (tid < SS) {
        cols[tid] = slot[l * SS + tid];
        gv[tid] = gen[b * SS + tid];
    }
    __syncthreads();
    float mval = -0.01f;
    bool isfirst = false;
    float merged = -0.01f;
    if (tid < SS) {
        int c = cols[tid];
        float sum = 0.f;
        int fi = SS;
        for (int s2 = 0; s2 < SS; ++s2) {
            if (cols[s2] == c) {
                sum += gv[s2];
                if (s2 < fi) fi = s2;
            }
        }
        merged = -0.01f + sum;
        mval = merged;
        isfirst = (fi == tid);
    }
    // block max
    red[tid] = mval;
    __syncthreads();
    for (int off = 128; off; off >>= 1) {
        if (tid < off) red[tid] = fmaxf(red[tid], red[tid + off]);
        __syncthreads();
    }
    float m = red[0];
    __syncthreads();
    // sum of exp over distinct hit columns
    float ex = (isfirst) ? expf(merged - m) : 0.f;
    red[tid] = ex;
    __syncthreads();
    for (int off = 128; off; off >>= 1) {
        if (tid < off) red[tid] += red[tid + off];
        __syncthreads();
    }
    float sum_hits = red[0];
    __syncthreads();
    // distinct count
    red[tid] = isfirst ? 1.f : 0.f;
    __syncthreads();
    for (int off = 128; off; off >>= 1) {
        if (tid < off) red[tid] += red[tid + off];
        __syncthreads();
    }
    float distinct = red[0];

    float base_e = expf(-0.01f - m);
    float denom = ((float)VV - distinct) * base_e + sum_hits;
    float inv = 1.f / denom;
    float pbase = base_e * inv;

    float* row = out + BB * HH + ((size_t)(l * BB + b)) * VV;
    float4 p4 = make_float4(pbase, pbase, pbase, pbase);
    float4* row4 = (float4*)row;
    for (int idx = tid; idx < VV / 4; idx += 256) row4[idx] = p4;
    __syncthreads();
    if (tid < SS && isfirst) row[cols[tid]] = expf(merged - m) * inv;
}

extern "C" void kernel_launch(void* const* d_in, const int* in_sizes, int n_in,
                              void* d_out, int out_size, void* d_ws, size_t ws_size,
                              hipStream_t stream) {
    const float* u_enc       = (const float*)d_in[0];
    const float* last_hidden = (const float*)d_in[1];
    const int*   z_tm1       = (const int*)d_in[2];
    const int*   slot        = (const int*)d_in[3];
    const float* emb_W       = (const float*)d_in[4];
    const float* ctrl_W      = (const float*)d_in[5];
    const float* ctrl_b      = (const float*)d_in[6];
    const float* attn_W      = (const float*)d_in[7];
    const float* attn_b      = (const float*)d_in[8];
    const float* attn_v      = (const float*)d_in[9];
    const float* Whid        = (const float*)d_in[10];
    const float* bhid        = (const float*)d_in[11];
    const float* Wout        = (const float*)d_in[12];
    const float* bout        = (const float*)d_in[13];
    float* out = (float*)d_out;
    float* ws = (float*)d_ws;

    float* scores   = ws;            // 32768
    float* wgt      = ws + 32768;    // 32768
    float* hW       = ws + 65536;    // 16384
    float* embed    = ws + 81920;    // 8192
    float* partial  = ws + 90112;    // 131072
    float* hiddenws = ws + 221184;   // 16384
    float* gen      = ws + 237568;   // 8192

    k_hw<<<BB, HH, 0, stream>>>(last_hidden, attn_W, attn_b, hW);
    k_embed<<<BB, EE, 0, stream>>>(z_tm1, emb_W, ctrl_W, ctrl_b, embed);
    k_scores<<<(TT * BB) / 64, 256, 0, stream>>>(u_enc, attn_W, attn_v, hW, scores);
    k_softmax<<<BB, 256, 0, stream>>>(scores, wgt);
    dim3 g2(8, BB);
    k_ctx_partial<<<g2, HH, 0, stream>>>(u_enc, wgt, partial);
    k_hidden<<<BB, HH, 0, stream>>>(embed, partial, last_hidden, Whid, bhid, hiddenws, out);
    k_gen<<<BB, SS, 0, stream>>>(hiddenws, Wout, bout, gen);
    k_probas<<<LL * BB, 256, 0, stream>>>(slot, gen, out);
}

// Round 2
// 104.752 us; speedup vs baseline: 1.7026x; 1.7026x over previous
//
#include <hip/hip_runtime.h>
#include <hip/hip_bf16.h>

#define BB 64
#define TT 512
#define HH 256
#define EE 128
#define VV 32000
#define SS 128
#define LL 16

typedef __attribute__((ext_vector_type(8))) short bf16x8;
typedef __attribute__((ext_vector_type(4))) float f32x4;

static __device__ __forceinline__ unsigned short f2bf(float x) {
    unsigned int u = __float_as_uint(x);
    unsigned int r = (u + 0x7fffu + ((u >> 16) & 1u)) >> 16;
    return (unsigned short)r;
}

// ---------- A1: hW[b,h] = attn_b[h] + sum_k last_hidden[b,k]*attn_W[h,k] ----------
__global__ __launch_bounds__(HH) void k_hw(const float* __restrict__ last_hidden,
                                           const float* __restrict__ attn_W,
                                           const float* __restrict__ attn_b,
                                           float* __restrict__ hW) {
    int b = blockIdx.x;
    int h = threadIdx.x;
    __shared__ float lh[HH];
    lh[h] = last_hidden[b * HH + h];
    __syncthreads();
    const float4* wrow = (const float4*)(attn_W + (size_t)h * (2 * HH));
    float acc = attn_b[h];
    for (int k4 = 0; k4 < HH / 4; ++k4) {
        float4 w = wrow[k4];
        acc += lh[k4*4+0]*w.x + lh[k4*4+1]*w.y + lh[k4*4+2]*w.z + lh[k4*4+3]*w.w;
    }
    hW[b * HH + h] = acc;
}

// ---------- A2: embed_z[b,:] = e + e @ ctrl_W.T + ctrl_b ----------
__global__ __launch_bounds__(EE) void k_embed(const int* __restrict__ z_tm1,
                                              const float* __restrict__ emb_W,
                                              const float* __restrict__ ctrl_W,
                                              const float* __restrict__ ctrl_b,
                                              float* __restrict__ embed) {
    int b = blockIdx.x;
    int j = threadIdx.x;  // 128
    __shared__ float e[EE];
    int z = z_tm1[b];
    e[j] = emb_W[(size_t)z * EE + j];
    __syncthreads();
    const float4* wrow = (const float4*)(ctrl_W + (size_t)j * EE);
    float acc = ctrl_b[j] + e[j];
    for (int k4 = 0; k4 < EE / 4; ++k4) {
        float4 w = wrow[k4];
        acc += e[k4*4+0]*w.x + e[k4*4+1]*w.y + e[k4*4+2]*w.z + e[k4*4+3]*w.w;
    }
    embed[b * EE + j] = acc;
}

// ---------- B-prep: swizzle attn_W[:, H:2H] into MFMA B-fragment order (bf16) ----------
// Bs layout: [kstep 0..7][tile 0..15][lane 0..63][8 bf16], 16B per (kstep,tile,lane).
// Fragment semantics: col = tile*16 + (lane&15), k = kstep*32 + (lane>>4)*8 + j.
__global__ __launch_bounds__(256) void k_prep_b(const float* __restrict__ attn_W,
                                                unsigned short* __restrict__ Bs) {
    int idx = blockIdx.x * 256 + threadIdx.x;  // 8192 total
    int lane = idx & 63;
    int gt = (idx >> 6) & 15;
    int ks = idx >> 10;
    int col = gt * 16 + (lane & 15);
    int k0 = ks * 32 + (lane >> 4) * 8;
    const float* src = attn_W + (size_t)col * (2 * HH) + HH + k0;
    unsigned int p0 = f2bf(src[0]) | ((unsigned int)f2bf(src[1]) << 16);
    unsigned int p1 = f2bf(src[2]) | ((unsigned int)f2bf(src[3]) << 16);
    unsigned int p2 = f2bf(src[4]) | ((unsigned int)f2bf(src[5]) << 16);
    unsigned int p3 = f2bf(src[6]) | ((unsigned int)f2bf(src[7]) << 16);
    uint4 pk = make_uint4(p0, p1, p2, p3);
    *(uint4*)(Bs + (size_t)idx * 8) = pk;
}

// ---------- B: scores via bf16 MFMA ----------
// block = (t-chunk, b): 64 t-rows for one fixed b. 4 waves, wave w owns cols [w*64, w*64+64).
__global__ __launch_bounds__(256) void k_scores_mfma(const float* __restrict__ enc,
                                                     const unsigned short* __restrict__ Bs,
                                                     const float* __restrict__ attn_v,
                                                     const float* __restrict__ hW,
                                                     float* __restrict__ scores) {
    __shared__ uint4 AbufV[2048];      // 32 KB: 64 rows x 256 k bf16, XOR-swizzled
    __shared__ float scpart[4][64];
    unsigned char* Abuf = (unsigned char*)AbufV;

    int tchunk = blockIdx.x;
    int b = blockIdx.y;
    int t0 = tchunk * 64;
    int tid = threadIdx.x;

    // stage A: f32 -> bf16, row-swizzled: addr = (row*512 + kc*16) ^ ((row&7)<<4)
#pragma unroll
    for (int it = 0; it < 8; ++it) {
        int c = tid + it * 256;     // 0..2047
        int row = c >> 5;
        int kc = c & 31;
        const float* src = enc + ((size_t)(t0 + row) * BB + b) * HH + kc * 8;
        float4 f0 = *(const float4*)src;
        float4 f1 = *(const float4*)(src + 4);
        unsigned int p0 = f2bf(f0.x) | ((unsigned int)f2bf(f0.y) << 16);
        unsigned int p1 = f2bf(f0.z) | ((unsigned int)f2bf(f0.w) << 16);
        unsigned int p2 = f2bf(f1.x) | ((unsigned int)f2bf(f1.y) << 16);
        unsigned int p3 = f2bf(f1.z) | ((unsigned int)f2bf(f1.w) << 16);
        int addr = (row * 512 + kc * 16) ^ ((row & 7) << 4);
        *(uint4*)(Abuf + addr) = make_uint4(p0, p1, p2, p3);
    }
    __syncthreads();

    int w = tid >> 6, lane = tid & 63;
    int lrow = lane & 15, q = lane >> 4;

    f32x4 acc[4][4];
#pragma unroll
    for (int rt = 0; rt < 4; ++rt)
#pragma unroll
        for (int ct = 0; ct < 4; ++ct) acc[rt][ct] = (f32x4){0.f, 0.f, 0.f, 0.f};

    const bf16x8* BsV = (const bf16x8*)Bs;
    for (int ks = 0; ks < 8; ++ks) {
        bf16x8 bfr[4];
        const bf16x8* bsrc = BsV + ((size_t)(ks * 16 + w * 4) * 64 + lane);
#pragma unroll
        for (int ct = 0; ct < 4; ++ct) bfr[ct] = bsrc[ct * 64];
        bf16x8 afr[4];
#pragma unroll
        for (int rt = 0; rt < 4; ++rt) {
            int arow = rt * 16 + lrow;
            int abyte = (arow * 512 + ks * 64 + q * 16) ^ ((arow & 7) << 4);
            afr[rt] = *(const bf16x8*)(Abuf + abyte);
        }
#pragma unroll
        for (int rt = 0; rt < 4; ++rt)
#pragma unroll
            for (int ct = 0; ct < 4; ++ct)
                acc[rt][ct] = __builtin_amdgcn_mfma_f32_16x16x32_bf16(afr[rt], bfr[ct], acc[rt][ct], 0, 0, 0);
    }

    // epilogue: scores[t,b] = sum_h v[h]*tanh(E + hW[b,h])
    float vv[4], hwv[4];
#pragma unroll
    for (int ct = 0; ct < 4; ++ct) {
        int col = w * 64 + ct * 16 + lrow;
        vv[ct] = attn_v[col];
        hwv[ct] = hW[(size_t)b * HH + col];
    }
#pragma unroll
    for (int rt = 0; rt < 4; ++rt) {
        float ps[4];
#pragma unroll
        for (int r = 0; r < 4; ++r) {
            float s = 0.f;
#pragma unroll
            for (int ct = 0; ct < 4; ++ct)
                s += vv[ct] * tanhf(acc[rt][ct][r] + hwv[ct]);
            ps[r] = s;
        }
#pragma unroll
        for (int r = 0; r < 4; ++r) {
#pragma unroll
            for (int off = 1; off < 16; off <<= 1) ps[r] += __shfl_xor(ps[r], off, 64);
        }
        if (lrow == 0) {
#pragma unroll
            for (int r = 0; r < 4; ++r) scpart[w][rt * 16 + q * 4 + r] = ps[r];
        }
    }
    __syncthreads();
    if (tid < 64) {
        float s = scpart[0][tid] + scpart[1][tid] + scpart[2][tid] + scpart[3][tid];
        scores[(size_t)(t0 + tid) * BB + b] = s;
    }
}

// ---------- C1: softmax over T per b ----------
__global__ __launch_bounds__(256) void k_softmax(const float* __restrict__ scores,
                                                 float* __restrict__ wgt) {
    int b = blockIdx.x, tid = threadIdx.x;
    __shared__ float red[256];
    float s0 = scores[tid * BB + b];
    float s1 = scores[(tid + 256) * BB + b];
    red[tid] = fmaxf(s0, s1);
    __syncthreads();
    for (int off = 128; off; off >>= 1) {
        if (tid < off) red[tid] = fmaxf(red[tid], red[tid + off]);
        __syncthreads();
    }
    float m = red[0];
    __syncthreads();
    float e0 = expf(s0 - m), e1 = expf(s1 - m);
    red[tid] = e0 + e1;
    __syncthreads();
    for (int off = 128; off; off >>= 1) {
        if (tid < off) red[tid] += red[tid + off];
        __syncthreads();
    }
    float inv = 1.f / red[0];
    wgt[tid * BB + b] = e0 * inv;
    wgt[(tid + 256) * BB + b] = e1 * inv;
}

// ---------- C2: context partials over t-chunks ----------
__global__ __launch_bounds__(HH) void k_ctx_partial(const float* __restrict__ enc,
                                                    const float* __restrict__ wgt,
                                                    float* __restrict__ partial) {
    int c = blockIdx.x;   // 0..7
    int b = blockIdx.y;   // 0..63
    int h = threadIdx.x;  // 0..255
    float acc = 0.f;
    for (int t = c * 64; t < c * 64 + 64; ++t) {
        acc += wgt[t * BB + b] * enc[((size_t)t * BB + b) * HH + h];
    }
    partial[((size_t)c * BB + b) * HH + h] = acc;
}

// ---------- D: hidden = relu(ffnn_in @ Whid.T + bhid) ----------
__global__ __launch_bounds__(HH) void k_hidden(const float* __restrict__ embed,
                                               const float* __restrict__ partial,
                                               const float* __restrict__ last_hidden,
                                               const float* __restrict__ Whid,
                                               const float* __restrict__ bhid,
                                               float* __restrict__ hidden_ws,
                                               float* __restrict__ out_hidden) {
    int b = blockIdx.x;
    int tid = threadIdx.x;  // 256
    __shared__ float fin[2 * HH + EE];  // 640
    for (int j = tid; j < 2 * HH + EE; j += 256) {
        float vv;
        if (j < EE) {
            vv = embed[b * EE + j];
        } else if (j < EE + HH) {
            float s = 0.f;
            for (int c = 0; c < 8; ++c) s += partial[((size_t)c * BB + b) * HH + (j - EE)];
            vv = s;
        } else {
            vv = last_hidden[b * HH + (j - EE - HH)];
        }
        fin[j] = vv;
    }
    __syncthreads();
    const float4* wrow = (const float4*)(Whid + (size_t)tid * (2 * HH + EE));
    float acc = bhid[tid];
    for (int k4 = 0; k4 < (2 * HH + EE) / 4; ++k4) {
        float4 w = wrow[k4];
        acc += fin[k4*4+0]*w.x + fin[k4*4+1]*w.y + fin[k4*4+2]*w.z + fin[k4*4+3]*w.w;
    }
    acc = fmaxf(acc, 0.f);
    hidden_ws[b * HH + tid] = acc;
    out_hidden[b * HH + tid] = acc;
}

// ---------- E: gen_score = relu(hidden @ Wout.T + bout) ----------
__global__ __launch_bounds__(SS) void k_gen(const float* __restrict__ hidden,
                                            const float* __restrict__ Wout,
                                            const float* __restrict__ bout,
                                            float* __restrict__ gen) {
    int b = blockIdx.x;
    int s = threadIdx.x;  // 128
    __shared__ float hsh[HH];
    hsh[s] = hidden[b * HH + s];
    hsh[s + 128] = hidden[b * HH + s + 128];
    __syncthreads();
    const float4* wrow = (const float4*)(Wout + (size_t)s * HH);
    float acc = bout[s];
    for (int k4 = 0; k4 < HH / 4; ++k4) {
        float4 w = wrow[k4];
        acc += hsh[k4*4+0]*w.x + hsh[k4*4+1]*w.y + hsh[k4*4+2]*w.z + hsh[k4*4+3]*w.w;
    }
    gen[b * SS + s] = fmaxf(acc, 0.f);
}

// ---------- F: probas rows — analytic softmax of (-0.01 + scatter) ----------
__global__ __launch_bounds__(256) void k_probas(const int* __restrict__ slot,
                                                const float* __restrict__ gen,
                                                float* __restrict__ out) {
    int l = blockIdx.x / BB;
    int b = blockIdx.x % BB;
    int tid = threadIdx.x;
    __shared__ int cols[SS];
    __shared__ float gv[SS];
    __shared__ float red[256];
    if (tid < SS) {
        cols[tid] = slot[l * SS + tid];
        gv[tid] = gen[b * SS + tid];
    }
    __syncthreads();
    float mval = -0.01f;
    bool isfirst = false;
    float merged = -0.01f;
    if (tid < SS) {
        int c = cols[tid];
        float sum = 0.f;
        int fi = SS;
        for (int s2 = 0; s2 < SS; ++s2) {
            if (cols[s2] == c) {
                sum += gv[s2];
                if (s2 < fi) fi = s2;
            }
        }
        merged = -0.01f + sum;
        mval = merged;
        isfirst = (fi == tid);
    }
    red[tid] = mval;
    __syncthreads();
    for (int off = 128; off; off >>= 1) {
        if (tid < off) red[tid] = fmaxf(red[tid], red[tid + off]);
        __syncthreads();
    }
    float m = red[0];
    __syncthreads();
    float ex = (isfirst) ? expf(merged - m) : 0.f;
    red[tid] = ex;
    __syncthreads();
    for (int off = 128; off; off >>= 1) {
        if (tid < off) red[tid] += red[tid + off];
        __syncthreads();
    }
    float sum_hits = red[0];
    __syncthreads();
    red[tid] = isfirst ? 1.f : 0.f;
    __syncthreads();
    for (int off = 128; off; off >>= 1) {
        if (tid < off) red[tid] += red[tid + off];
        __syncthreads();
    }
    float distinct = red[0];

    float base_e = expf(-0.01f - m);
    float denom = ((float)VV - distinct) * base_e + sum_hits;
    float inv = 1.f / denom;
    float pbase = base_e * inv;

    float* row = out + BB * HH + ((size_t)(l * BB + b)) * VV;
    float4 p4 = make_float4(pbase, pbase, pbase, pbase);
    float4* row4 = (float4*)row;
    for (int idx = tid; idx < VV / 4; idx += 256) row4[idx] = p4;
    __syncthreads();
    if (tid < SS && isfirst) row[cols[tid]] = expf(merged - m) * inv;
}

extern "C" void kernel_launch(void* const* d_in, const int* in_sizes, int n_in,
                              void* d_out, int out_size, void* d_ws, size_t ws_size,
                              hipStream_t stream) {
    const float* u_enc       = (const float*)d_in[0];
    const float* last_hidden = (const float*)d_in[1];
    const int*   z_tm1       = (const int*)d_in[2];
    const int*   slot        = (const int*)d_in[3];
    const float* emb_W       = (const float*)d_in[4];
    const float* ctrl_W      = (const float*)d_in[5];
    const float* ctrl_b      = (const float*)d_in[6];
    const float* attn_W      = (const float*)d_in[7];
    const float* attn_b      = (const float*)d_in[8];
    const float* attn_v      = (const float*)d_in[9];
    const float* Whid        = (const float*)d_in[10];
    const float* bhid        = (const float*)d_in[11];
    const float* Wout        = (const float*)d_in[12];
    const float* bout        = (const float*)d_in[13];
    float* out = (float*)d_out;
    float* ws = (float*)d_ws;

    float* scores   = ws;            // 32768
    float* wgt      = ws + 32768;    // 32768
    float* hW       = ws + 65536;    // 16384
    float* embed    = ws + 81920;    // 8192
    float* partial  = ws + 90112;    // 131072
    float* hiddenws = ws + 221184;   // 16384
    float* gen      = ws + 237568;   // 8192
    unsigned short* Bs = (unsigned short*)(ws + 245760);  // 65536 bf16 = 32768 floats

    k_hw<<<BB, HH, 0, stream>>>(last_hidden, attn_W, attn_b, hW);
    k_prep_b<<<32, 256, 0, stream>>>(attn_W, Bs);
    k_embed<<<BB, EE, 0, stream>>>(z_tm1, emb_W, ctrl_W, ctrl_b, embed);
    dim3 gs(TT / 64, BB);
    k_scores_mfma<<<gs, 256, 0, stream>>>(u_enc, Bs, attn_v, hW, scores);
    k_softmax<<<BB, 256, 0, stream>>>(scores, wgt);
    dim3 g2(8, BB);
    k_ctx_partial<<<g2, HH, 0, stream>>>(u_enc, wgt, partial);
    k_hidden<<<BB, HH, 0, stream>>>(embed, partial, last_hidden, Whid, bhid, hiddenws, out);
    k_gen<<<BB, SS, 0, stream>>>(hiddenws, Wout, bout, gen);
    k_probas<<<LL * BB, 256, 0, stream>>>(slot, gen, out);
}